// Round 2
// baseline (627.824 us; speedup 1.0000x reference)
//
#include <hip/hip_runtime.h>
#include <hip/hip_bf16.h>

// MFW encdec multihead attention, MI355X.
// Pipeline: build W (lowrank-adapted) -> fp16 GEMM q,k -> bf16 GEMM v ->
// scores+softmax (fp16 MFMA, f32 softmax, probs->d_out f32) -> PV (bf16) -> out GEMM (f32 out).
// NOTE: d_out is FLOAT32 (reference returns float32 outputs).

typedef float  fx4 __attribute__((ext_vector_type(4)));
typedef short  sx8 __attribute__((ext_vector_type(8)));
typedef _Float16 hx8 __attribute__((ext_vector_type(8)));

__device__ __forceinline__ unsigned short f2bf_rne(float f) {
  unsigned u = __builtin_bit_cast(unsigned, f);
  u += 0x7FFFu + ((u >> 16) & 1u);
  return (unsigned short)(u >> 16);
}
__device__ __forceinline__ unsigned short f2h(float f) {
  return __builtin_bit_cast(unsigned short, (_Float16)f);
}

__device__ __forceinline__ void gload_lds16(const void* g, void* l) {
  __builtin_amdgcn_global_load_lds((const __attribute__((address_space(1))) void*)g,
                                   (__attribute__((address_space(3))) void*)l, 16, 0, 0);
}

__device__ __forceinline__ fx4 mfma_h(sx8 a, sx8 b, fx4 c) {
  return __builtin_amdgcn_mfma_f32_16x16x32_f16(__builtin_bit_cast(hx8, a),
                                                __builtin_bit_cast(hx8, b), c, 0, 0, 0);
}
__device__ __forceinline__ fx4 mfma_b(sx8 a, sx8 b, fx4 c) {
  return __builtin_amdgcn_mfma_f32_16x16x32_bf16(a, b, c, 0, 0, 0);
}

// ---------------------------------------------------------------------------
// Kernel 1: build adapted weights.
// mat 0: Wq (fp16, scaled by 0.125)  1: Wk (fp16)  2: Wv (bf16)  3: Wo (bf16)
// ---------------------------------------------------------------------------
__global__ void k_build_w(
    const float* wq, const float* wkv, const float* wo,
    const float* r_q, const float* s_q, const float* r_kv, const float* s_kv,
    const float* r_o, const float* s_o,
    const float* rm_q, const float* sm_q, const float* rm_kv, const float* sm_kv,
    const float* rm_o, const float* sm_o,
    const int* src_i, const int* tgt_i,
    unsigned short* Wq16, unsigned short* Wk16, unsigned short* Wv, unsigned short* Wo)
{
  const int it = tgt_i[0], is = src_i[0];
  const int gid = blockIdx.x * 256 + threadIdx.x;   // 0 .. 4*1024*1024-1
  const int mat = gid >> 20;
  const int idx = gid & 1048575;
  const int o = idx >> 10, i = idx & 1023;
  float lrm = 0.f, lr = 0.f, w;
  if (mat == 0) {
    #pragma unroll
    for (int r = 0; r < 4; ++r) {
      lrm += rm_q[(it * 4 + r) * 1024 + o] * sm_q[(is * 4 + r) * 1024 + i];
      lr  += r_q [(it * 4 + r) * 1024 + o] * s_q [(is * 4 + r) * 1024 + i];
    }
    w = (wq[idx] * lrm + lr) * 0.125f;   // fold q scaling into Wq
    Wq16[idx] = f2h(w);
  } else if (mat == 1) {
    #pragma unroll
    for (int r = 0; r < 4; ++r) {
      lrm += rm_kv[(it * 4 + r) * 2048 + o] * sm_kv[(is * 4 + r) * 1024 + i];
      lr  += r_kv [(it * 4 + r) * 2048 + o] * s_kv [(is * 4 + r) * 1024 + i];
    }
    w = wkv[idx] * lrm + lr;
    Wk16[idx] = f2h(w);
  } else if (mat == 2) {
    #pragma unroll
    for (int r = 0; r < 4; ++r) {
      lrm += rm_kv[(it * 4 + r) * 2048 + 1024 + o] * sm_kv[(is * 4 + r) * 1024 + i];
      lr  += r_kv [(it * 4 + r) * 2048 + 1024 + o] * s_kv [(is * 4 + r) * 1024 + i];
    }
    w = wkv[1048576 + idx] * lrm + lr;
    Wv[idx] = f2bf_rne(w);
  } else {
    #pragma unroll
    for (int r = 0; r < 4; ++r) {
      lrm += rm_o[(it * 4 + r) * 1024 + o] * sm_o[(is * 4 + r) * 1024 + i];
      lr  += r_o [(it * 4 + r) * 1024 + o] * s_o [(is * 4 + r) * 1024 + i];
    }
    w = wo[idx] * lrm + lr;
    Wo[idx] = f2bf_rne(w);
  }
}

// ---------------------------------------------------------------------------
// Kernel 2: C = A * B^T, M=8192, N=1024, K=1024.  128x128 tile, BK=32, 4 waves.
// MODE 0: A f32 -> fp16 staged, B fp16, C fp16       (q / k projections)
// MODE 1: A f32 -> bf16 staged, B bf16, C bf16       (v projection)
// MODE 2: A bf16 (global_load_lds), B bf16, C f32    (out projection -> d_out)
// ---------------------------------------------------------------------------
template<int MODE>
__global__ __launch_bounds__(256, 2) void k_gemm(
    const float* Af, const unsigned short* Ab,
    const unsigned short* Bmat, unsigned short* Ch, float* Cf)
{
  __shared__ unsigned short lds[2][2][4096];   // [buf][A=0/B=1][128*32]
  const int tid = threadIdx.x;
  const int l = tid & 63, wid = tid >> 6;
  const int wr = wid >> 1, wc = wid & 1;
  const int mBase = blockIdx.y * 128, nBase = blockIdx.x * 128;

  const int arow = tid >> 1, ac16 = (tid & 1) * 16;
  const int brow = tid >> 2, bc8 = (tid & 3) * 8;

  fx4 acc[4][4] = {};

  auto stage = [&](int buf, int kt) {
    const int kB = kt * 32;
    gload_lds16(Bmat + (size_t)(nBase + brow) * 1024 + kB + bc8,      &lds[buf][1][tid * 8]);
    gload_lds16(Bmat + (size_t)(nBase + 64 + brow) * 1024 + kB + bc8, &lds[buf][1][2048 + tid * 8]);
    if constexpr (MODE == 2) {
      gload_lds16(Ab + (size_t)(mBase + brow) * 1024 + kB + bc8,      &lds[buf][0][tid * 8]);
      gload_lds16(Ab + (size_t)(mBase + 64 + brow) * 1024 + kB + bc8, &lds[buf][0][2048 + tid * 8]);
    } else {
      const float* asrc = Af + (size_t)(mBase + arow) * 1024 + kB + ac16;
      sx8 h0, h1;
      #pragma unroll
      for (int p = 0; p < 4; ++p) {
        fx4 vv = *(const fx4*)(asrc + p * 4);
        #pragma unroll
        for (int j = 0; j < 4; ++j) {
          unsigned short hv;
          if constexpr (MODE == 0) hv = f2h(vv[j]); else hv = f2bf_rne(vv[j]);
          const int pos = p * 4 + j;
          if (pos < 8) h0[pos] = (short)hv; else h1[pos - 8] = (short)hv;
        }
      }
      *(sx8*)&lds[buf][0][arow * 32 + ac16]     = h0;
      *(sx8*)&lds[buf][0][arow * 32 + ac16 + 8] = h1;
    }
  };

  auto compute = [&](int buf) {
    sx8 af[4], bfv[4];
    #pragma unroll
    for (int x = 0; x < 4; ++x) {
      af[x]  = *(const sx8*)&lds[buf][0][(wr * 64 + x * 16 + (l & 15)) * 32 + (l >> 4) * 8];
      bfv[x] = *(const sx8*)&lds[buf][1][(wc * 64 + x * 16 + (l & 15)) * 32 + (l >> 4) * 8];
    }
    #pragma unroll
    for (int mi = 0; mi < 4; ++mi)
      #pragma unroll
      for (int ni = 0; ni < 4; ++ni) {
        if constexpr (MODE == 0) acc[mi][ni] = mfma_h(af[mi], bfv[ni], acc[mi][ni]);
        else                     acc[mi][ni] = mfma_b(af[mi], bfv[ni], acc[mi][ni]);
      }
  };

  stage(0, 0);
  __syncthreads();
  for (int kt = 0; kt < 32; ++kt) {
    const int buf = kt & 1;
    if (kt + 1 < 32) stage(buf ^ 1, kt + 1);
    compute(buf);
    __syncthreads();
  }

  #pragma unroll
  for (int mi = 0; mi < 4; ++mi)
    #pragma unroll
    for (int ni = 0; ni < 4; ++ni)
      #pragma unroll
      for (int i = 0; i < 4; ++i) {
        const size_t row = (size_t)(mBase + wr * 64 + mi * 16 + (l >> 4) * 4 + i);
        const size_t col = (size_t)(nBase + wc * 64 + ni * 16 + (l & 15));
        const float x = acc[mi][ni][i];
        if constexpr (MODE == 0)      Ch[row * 1024 + col] = f2h(x);
        else if constexpr (MODE == 1) Ch[row * 1024 + col] = f2bf_rne(x);
        else                          Cf[row * 1024 + col] = x;
      }
}

// ---------------------------------------------------------------------------
// Kernel 3: scores + softmax -> probs (f32, straight to d_out).
// Block = (head, 64 q-rows), 8 waves: wave (qg, half) does 16 q x 512 k.
// Scores live in 32 f32x4 acc regs. k-tiles staged in LDS with XOR swizzle
// (pre-swizzled global source, linear global_load_lds dest).
// ---------------------------------------------------------------------------
__global__ __launch_bounds__(512, 2) void k_scores(
    const unsigned short* q16, const unsigned short* k16, float* probsF)
{
  __shared__ unsigned short kt_lds[2][2][1024];  // [buf][half][16 k x 64 d]
  __shared__ float redmax[4][16][2], redsum[4][16][2];
  const int tid = threadIdx.x, l = tid & 63, wid = tid >> 6;
  const int qg = wid >> 1, half = wid & 1;
  const int head = blockIdx.x >> 4, qb = blockIdx.x & 15;
  const int b = head >> 4, hh = head & 15;

  sx8 qf[2];
  {
    const int lqa = qb * 64 + qg * 16 + (l & 15);
    const size_t qoff = (size_t)(lqa * 8 + b) * 1024 + hh * 64 + (l >> 4) * 8;
    qf[0] = *(const sx8*)&q16[qoff];
    qf[1] = *(const sx8*)&q16[qoff + 32];
  }

  fx4 acc[32];
  #pragma unroll
  for (int s = 0; s < 32; ++s) acc[s] = fx4{0.f, 0.f, 0.f, 0.f};

  auto stage = [&](int buf, int s) {
    if (tid < 256) {
      const int half_s = tid >> 7, i = tid & 127;
      const int row = i >> 3, cphys = i & 7;
      const int clog = cphys ^ (row & 7);          // pre-swizzled source
      const int lk = half_s * 512 + s * 16 + row;
      gload_lds16(k16 + (size_t)(lk * 8 + b) * 1024 + hh * 64 + clog * 8,
                  &kt_lds[buf][half_s][i * 8]);
    }
  };

  stage(0, 0);
  __syncthreads();
  #pragma unroll
  for (int s = 0; s < 32; ++s) {
    const int buf = s & 1;
    if (s + 1 < 32) stage(buf ^ 1, s + 1);
    sx8 bh0, bh1;
    {
      const int row = l & 15;
      const int c0 = (0 * 4 + (l >> 4)) ^ (row & 7);
      const int c1 = (1 * 4 + (l >> 4)) ^ (row & 7);
      bh0 = *(const sx8*)&kt_lds[buf][half][row * 64 + c0 * 8];
      bh1 = *(const sx8*)&kt_lds[buf][half][row * 64 + c1 * 8];
    }
    acc[s] = mfma_h(qf[0], bh0, acc[s]);
    acc[s] = mfma_h(qf[1], bh1, acc[s]);
    __syncthreads();
  }

  // softmax: lane holds rows rg*4+i (i<4), cols (l&15)+16*s in its 512-half.
  const int rg = l >> 4;
  float mloc[4] = {-3e38f, -3e38f, -3e38f, -3e38f};
  #pragma unroll
  for (int s = 0; s < 32; ++s)
    #pragma unroll
    for (int i = 0; i < 4; ++i) mloc[i] = fmaxf(mloc[i], acc[s][i]);
  #pragma unroll
  for (int msk = 1; msk <= 8; msk <<= 1)
    #pragma unroll
    for (int i = 0; i < 4; ++i) mloc[i] = fmaxf(mloc[i], __shfl_xor(mloc[i], msk));
  if ((l & 15) == 0) {
    #pragma unroll
    for (int i = 0; i < 4; ++i) redmax[qg][rg * 4 + i][half] = mloc[i];
  }
  __syncthreads();
  float mfull[4], sloc[4] = {0.f, 0.f, 0.f, 0.f};
  #pragma unroll
  for (int i = 0; i < 4; ++i)
    mfull[i] = fmaxf(redmax[qg][rg * 4 + i][0], redmax[qg][rg * 4 + i][1]);
  #pragma unroll
  for (int s = 0; s < 32; ++s)
    #pragma unroll
    for (int i = 0; i < 4; ++i) {
      const float e = __expf(acc[s][i] - mfull[i]);
      acc[s][i] = e;
      sloc[i] += e;
    }
  #pragma unroll
  for (int msk = 1; msk <= 8; msk <<= 1)
    #pragma unroll
    for (int i = 0; i < 4; ++i) sloc[i] += __shfl_xor(sloc[i], msk);
  if ((l & 15) == 0) {
    #pragma unroll
    for (int i = 0; i < 4; ++i) redsum[qg][rg * 4 + i][half] = sloc[i];
  }
  __syncthreads();
  float inv[4];
  #pragma unroll
  for (int i = 0; i < 4; ++i)
    inv[i] = 1.0f / (redsum[qg][rg * 4 + i][0] + redsum[qg][rg * 4 + i][1]);

  const size_t pbase = (size_t)head * 1048576;
  const int lqs = qb * 64 + qg * 16 + rg * 4;
  #pragma unroll
  for (int s = 0; s < 32; ++s)
    #pragma unroll
    for (int i = 0; i < 4; ++i)
      probsF[pbase + (size_t)(lqs + i) * 1024 + half * 512 + s * 16 + (l & 15)] =
          acc[s][i] * inv[i];
}

// ---------------------------------------------------------------------------
// Kernel 4: ctx = probs @ v per head.  Block = (head, 128 q), tile 128x64,
// 4 waves (2x2), BK=32.  P staged f32->bf16 into LDS; v transposed into
// padded LDS ([64][40]).  ctx written in (lq, b, E) layout, bf16.
// ---------------------------------------------------------------------------
__global__ __launch_bounds__(256, 2) void k_pv(
    const float* probsF, const unsigned short* v_, unsigned short* ctx)
{
  __shared__ unsigned short pt[2][4096];      // [128 q][32 k]
  __shared__ unsigned short vt[2][64 * 40];   // [64 d][32 k + pad 8]
  const int tid = threadIdx.x, l = tid & 63, wid = tid >> 6;
  const int wr = wid >> 1, wc = wid & 1;
  const int head = blockIdx.x >> 3, mb = blockIdx.x & 7;
  const int b = head >> 4, hh = head & 15;
  const size_t pbase = (size_t)head * 1048576;

  fx4 acc[4][2] = {};

  auto stage = [&](int buf, int kt) {
    const int kb = kt * 32;
    // P: 128 rows x 32 k, f32 -> bf16
    const int prow = tid >> 1, pc16 = (tid & 1) * 16;
    const float* psrc = probsF + pbase + (size_t)(mb * 128 + prow) * 1024 + kb + pc16;
    sx8 h0, h1;
    #pragma unroll
    for (int p = 0; p < 4; ++p) {
      fx4 vv = *(const fx4*)(psrc + p * 4);
      #pragma unroll
      for (int j = 0; j < 4; ++j) {
        const unsigned short hv = f2bf_rne(vv[j]);
        const int pos = p * 4 + j;
        if (pos < 8) h0[pos] = (short)hv; else h1[pos - 8] = (short)hv;
      }
    }
    *(sx8*)&pt[buf][prow * 32 + pc16]     = h0;
    *(sx8*)&pt[buf][prow * 32 + pc16 + 8] = h1;
    // V: 32 k x 64 d, transposed
    sx8 vv = *(const sx8*)&v_[(size_t)((kb + (tid >> 3)) * 8 + b) * 1024 + hh * 64 + (tid & 7) * 8];
    #pragma unroll
    for (int j = 0; j < 8; ++j)
      vt[buf][((tid & 7) * 8 + j) * 40 + (tid >> 3)] = (unsigned short)vv[j];
  };

  stage(0, 0);
  __syncthreads();
  for (int kt = 0; kt < 32; ++kt) {
    const int buf = kt & 1;
    if (kt + 1 < 32) stage(buf ^ 1, kt + 1);
    sx8 af[4], bfr[2];
    #pragma unroll
    for (int mi = 0; mi < 4; ++mi)
      af[mi] = *(const sx8*)&pt[buf][(wr * 64 + mi * 16 + (l & 15)) * 32 + (l >> 4) * 8];
    #pragma unroll
    for (int ni = 0; ni < 2; ++ni)
      bfr[ni] = *(const sx8*)&vt[buf][(wc * 32 + ni * 16 + (l & 15)) * 40 + (l >> 4) * 8];
    #pragma unroll
    for (int mi = 0; mi < 4; ++mi)
      #pragma unroll
      for (int ni = 0; ni < 2; ++ni)
        acc[mi][ni] = mfma_b(af[mi], bfr[ni], acc[mi][ni]);
    __syncthreads();
  }

  #pragma unroll
  for (int mi = 0; mi < 4; ++mi)
    #pragma unroll
    for (int ni = 0; ni < 2; ++ni)
      #pragma unroll
      for (int i = 0; i < 4; ++i) {
        const int q = mb * 128 + wr * 64 + mi * 16 + (l >> 4) * 4 + i;
        const int col = wc * 32 + ni * 16 + (l & 15);
        ctx[(size_t)(q * 8 + b) * 1024 + hh * 64 + col] = f2bf_rne(acc[mi][ni][i]);
      }
}

// ---------------------------------------------------------------------------
extern "C" void kernel_launch(void* const* d_in, const int* in_sizes, int n_in,
                              void* d_out, int out_size, void* d_ws, size_t ws_size,
                              hipStream_t stream)
{
  const float* query = (const float*)d_in[0];
  const float* key   = (const float*)d_in[1];
  const float* wq    = (const float*)d_in[2];
  const float* wkv   = (const float*)d_in[3];
  const float* wo    = (const float*)d_in[4];
  const float* r_q   = (const float*)d_in[5];
  const float* s_q   = (const float*)d_in[6];
  const float* r_kv  = (const float*)d_in[7];
  const float* s_kv  = (const float*)d_in[8];
  const float* r_o   = (const float*)d_in[9];
  const float* s_o   = (const float*)d_in[10];
  const float* rm_q  = (const float*)d_in[11];
  const float* sm_q  = (const float*)d_in[12];
  const float* rm_kv = (const float*)d_in[13];
  const float* sm_kv = (const float*)d_in[14];
  const float* rm_o  = (const float*)d_in[15];
  const float* sm_o  = (const float*)d_in[16];
  const int* src_i   = (const int*)d_in[17];
  const int* tgt_i   = (const int*)d_in[18];

  unsigned short* ws16 = (unsigned short*)d_ws;
  const size_t M1 = 1048576, M8 = 8388608;
  unsigned short* Wq16 = ws16;
  unsigned short* Wk16 = ws16 + M1;
  unsigned short* Wv   = ws16 + 2 * M1;
  unsigned short* Wo   = ws16 + 3 * M1;
  unsigned short* q16  = ws16 + 4 * M1;
  unsigned short* k16  = ws16 + 4 * M1 + M8;
  unsigned short* v_   = ws16 + 4 * M1 + 2 * M8;
  unsigned short* ctx  = ws16 + 4 * M1 + 3 * M8;   // total ~72 MB

  float* outF   = (float*)d_out;            // out: 8388608 f32
  float* probsF = outF + M8;                // probs: 134217728 f32

  k_build_w<<<dim3(16384), dim3(256), 0, stream>>>(
      wq, wkv, wo, r_q, s_q, r_kv, s_kv, r_o, s_o,
      rm_q, sm_q, rm_kv, sm_kv, rm_o, sm_o, src_i, tgt_i,
      Wq16, Wk16, Wv, Wo);

  k_gemm<0><<<dim3(8, 64), dim3(256), 0, stream>>>(query, nullptr, Wq16, q16, nullptr);
  k_gemm<0><<<dim3(8, 64), dim3(256), 0, stream>>>(key,   nullptr, Wk16, k16, nullptr);
  k_gemm<1><<<dim3(8, 64), dim3(256), 0, stream>>>(key,   nullptr, Wv,   v_,  nullptr);

  k_scores<<<dim3(2048), dim3(512), 0, stream>>>(q16, k16, probsF);
  k_pv<<<dim3(1024), dim3(256), 0, stream>>>(probsF, v_, ctx);

  k_gemm<2><<<dim3(8, 64), dim3(256), 0, stream>>>(nullptr, ctx, Wo, nullptr, outF);
}

// Round 3
// 615.109 us; speedup vs baseline: 1.0207x; 1.0207x over previous
//
#include <hip/hip_runtime.h>
#include <hip/hip_bf16.h>

// MFW encdec multihead attention, MI355X.
// Pipeline: build W (lowrank-adapted) -> fp16 GEMM q,k -> bf16 GEMM v ->
// FUSED scores+softmax+PV (probs f32 -> d_out, P kept in LDS as bf16, ctx out)
// -> out GEMM (f32 -> d_out).
// d_out is FLOAT32: [out 8.4M | probs 134.2M].

typedef float  fx4 __attribute__((ext_vector_type(4)));
typedef short  sx8 __attribute__((ext_vector_type(8)));
typedef _Float16 hx8 __attribute__((ext_vector_type(8)));

__device__ __forceinline__ unsigned short f2bf_rne(float f) {
  unsigned u = __builtin_bit_cast(unsigned, f);
  u += 0x7FFFu + ((u >> 16) & 1u);
  return (unsigned short)(u >> 16);
}
__device__ __forceinline__ unsigned short f2h(float f) {
  return __builtin_bit_cast(unsigned short, (_Float16)f);
}

__device__ __forceinline__ void gload_lds16(const void* g, void* l) {
  __builtin_amdgcn_global_load_lds((const __attribute__((address_space(1))) void*)g,
                                   (__attribute__((address_space(3))) void*)l, 16, 0, 0);
}

__device__ __forceinline__ fx4 mfma_h(sx8 a, sx8 b, fx4 c) {
  return __builtin_amdgcn_mfma_f32_16x16x32_f16(__builtin_bit_cast(hx8, a),
                                                __builtin_bit_cast(hx8, b), c, 0, 0, 0);
}
__device__ __forceinline__ fx4 mfma_b(sx8 a, sx8 b, fx4 c) {
  return __builtin_amdgcn_mfma_f32_16x16x32_bf16(a, b, c, 0, 0, 0);
}

// ---------------------------------------------------------------------------
// Kernel 1: build adapted weights.
// mat 0: Wq (fp16, scaled by 0.125)  1: Wk (fp16)  2: Wv (bf16)  3: Wo (bf16)
// ---------------------------------------------------------------------------
__global__ void k_build_w(
    const float* wq, const float* wkv, const float* wo,
    const float* r_q, const float* s_q, const float* r_kv, const float* s_kv,
    const float* r_o, const float* s_o,
    const float* rm_q, const float* sm_q, const float* rm_kv, const float* sm_kv,
    const float* rm_o, const float* sm_o,
    const int* src_i, const int* tgt_i,
    unsigned short* Wq16, unsigned short* Wk16, unsigned short* Wv, unsigned short* Wo)
{
  const int it = tgt_i[0], is = src_i[0];
  const int gid = blockIdx.x * 256 + threadIdx.x;   // 0 .. 4*1024*1024-1
  const int mat = gid >> 20;
  const int idx = gid & 1048575;
  const int o = idx >> 10, i = idx & 1023;
  float lrm = 0.f, lr = 0.f, w;
  if (mat == 0) {
    #pragma unroll
    for (int r = 0; r < 4; ++r) {
      lrm += rm_q[(it * 4 + r) * 1024 + o] * sm_q[(is * 4 + r) * 1024 + i];
      lr  += r_q [(it * 4 + r) * 1024 + o] * s_q [(is * 4 + r) * 1024 + i];
    }
    w = (wq[idx] * lrm + lr) * 0.125f;   // fold q scaling into Wq
    Wq16[idx] = f2h(w);
  } else if (mat == 1) {
    #pragma unroll
    for (int r = 0; r < 4; ++r) {
      lrm += rm_kv[(it * 4 + r) * 2048 + o] * sm_kv[(is * 4 + r) * 1024 + i];
      lr  += r_kv [(it * 4 + r) * 2048 + o] * s_kv [(is * 4 + r) * 1024 + i];
    }
    w = wkv[idx] * lrm + lr;
    Wk16[idx] = f2h(w);
  } else if (mat == 2) {
    #pragma unroll
    for (int r = 0; r < 4; ++r) {
      lrm += rm_kv[(it * 4 + r) * 2048 + 1024 + o] * sm_kv[(is * 4 + r) * 1024 + i];
      lr  += r_kv [(it * 4 + r) * 2048 + 1024 + o] * s_kv [(is * 4 + r) * 1024 + i];
    }
    w = wkv[1048576 + idx] * lrm + lr;
    Wv[idx] = f2bf_rne(w);
  } else {
    #pragma unroll
    for (int r = 0; r < 4; ++r) {
      lrm += rm_o[(it * 4 + r) * 1024 + o] * sm_o[(is * 4 + r) * 1024 + i];
      lr  += r_o [(it * 4 + r) * 1024 + o] * s_o [(is * 4 + r) * 1024 + i];
    }
    w = wo[idx] * lrm + lr;
    Wo[idx] = f2bf_rne(w);
  }
}

// ---------------------------------------------------------------------------
// Kernel 2: C = A * B^T, M=8192, N=1024, K=1024.  128x128 tile, BK=32, 4 waves.
// MODE 0: A f32 -> fp16 staged, B fp16, C fp16       (q / k projections)
// MODE 1: A f32 -> bf16 staged, B bf16, C bf16       (v projection)
// MODE 2: A bf16 (global_load_lds), B bf16, C f32    (out projection -> d_out)
// ---------------------------------------------------------------------------
template<int MODE>
__global__ __launch_bounds__(256, 2) void k_gemm(
    const float* Af, const unsigned short* Ab,
    const unsigned short* Bmat, unsigned short* Ch, float* Cf)
{
  __shared__ unsigned short lds[2][2][4096];   // [buf][A=0/B=1][128*32]
  const int tid = threadIdx.x;
  const int l = tid & 63, wid = tid >> 6;
  const int wr = wid >> 1, wc = wid & 1;
  const int mBase = blockIdx.y * 128, nBase = blockIdx.x * 128;

  const int arow = tid >> 1, ac16 = (tid & 1) * 16;
  const int brow = tid >> 2, bc8 = (tid & 3) * 8;

  fx4 acc[4][4] = {};

  auto stage = [&](int buf, int kt) {
    const int kB = kt * 32;
    gload_lds16(Bmat + (size_t)(nBase + brow) * 1024 + kB + bc8,      &lds[buf][1][tid * 8]);
    gload_lds16(Bmat + (size_t)(nBase + 64 + brow) * 1024 + kB + bc8, &lds[buf][1][2048 + tid * 8]);
    if constexpr (MODE == 2) {
      gload_lds16(Ab + (size_t)(mBase + brow) * 1024 + kB + bc8,      &lds[buf][0][tid * 8]);
      gload_lds16(Ab + (size_t)(mBase + 64 + brow) * 1024 + kB + bc8, &lds[buf][0][2048 + tid * 8]);
    } else {
      const float* asrc = Af + (size_t)(mBase + arow) * 1024 + kB + ac16;
      sx8 h0, h1;
      #pragma unroll
      for (int p = 0; p < 4; ++p) {
        fx4 vv = *(const fx4*)(asrc + p * 4);
        #pragma unroll
        for (int j = 0; j < 4; ++j) {
          unsigned short hv;
          if constexpr (MODE == 0) hv = f2h(vv[j]); else hv = f2bf_rne(vv[j]);
          const int pos = p * 4 + j;
          if (pos < 8) h0[pos] = (short)hv; else h1[pos - 8] = (short)hv;
        }
      }
      *(sx8*)&lds[buf][0][arow * 32 + ac16]     = h0;
      *(sx8*)&lds[buf][0][arow * 32 + ac16 + 8] = h1;
    }
  };

  auto compute = [&](int buf) {
    sx8 af[4], bfv[4];
    #pragma unroll
    for (int x = 0; x < 4; ++x) {
      af[x]  = *(const sx8*)&lds[buf][0][(wr * 64 + x * 16 + (l & 15)) * 32 + (l >> 4) * 8];
      bfv[x] = *(const sx8*)&lds[buf][1][(wc * 64 + x * 16 + (l & 15)) * 32 + (l >> 4) * 8];
    }
    #pragma unroll
    for (int mi = 0; mi < 4; ++mi)
      #pragma unroll
      for (int ni = 0; ni < 4; ++ni) {
        if constexpr (MODE == 0) acc[mi][ni] = mfma_h(af[mi], bfv[ni], acc[mi][ni]);
        else                     acc[mi][ni] = mfma_b(af[mi], bfv[ni], acc[mi][ni]);
      }
  };

  stage(0, 0);
  __syncthreads();
  for (int kt = 0; kt < 32; ++kt) {
    const int buf = kt & 1;
    if (kt + 1 < 32) stage(buf ^ 1, kt + 1);
    compute(buf);
    __syncthreads();
  }

  #pragma unroll
  for (int mi = 0; mi < 4; ++mi)
    #pragma unroll
    for (int ni = 0; ni < 4; ++ni)
      #pragma unroll
      for (int i = 0; i < 4; ++i) {
        const size_t row = (size_t)(mBase + wr * 64 + mi * 16 + (l >> 4) * 4 + i);
        const size_t col = (size_t)(nBase + wc * 64 + ni * 16 + (l & 15));
        const float x = acc[mi][ni][i];
        if constexpr (MODE == 0)      Ch[row * 1024 + col] = f2h(x);
        else if constexpr (MODE == 1) Ch[row * 1024 + col] = f2bf_rne(x);
        else                          Cf[row * 1024 + col] = x;
      }
}

// ---------------------------------------------------------------------------
// Kernel 3 (FUSED): scores + softmax + probs-out + PV.
// Block = (head, 64 q), 512 threads, 8 waves.
// Phase 1 (QK^T): wave (qg, half) -> 16 q x 512 k in 32 fx4 acc regs.
// Phase 2: exact softmax (shfl_xor 16-groups + cross-half via LDS).
// Phase 3: probs f32 -> d_out AND P bf16 -> LDS [64][1024] (chunk-XOR swizzle).
// Phase 4 (PV): wave (qg, dh) -> 16 q x 32 d over full 1024 k; V streamed in
//               32-k chunks, transposed into LDS (reuses K-staging region).
// LDS total ~139 KB -> 1 block/CU (VGPR ~200 capped it there anyway).
// ---------------------------------------------------------------------------
__global__ __launch_bounds__(512, 2) void k_attn(
    const unsigned short* q16, const unsigned short* k16,
    const unsigned short* v_, float* probsF, unsigned short* ctx)
{
  __shared__ __align__(16) unsigned short Pl[65536];        // [64 q][1024 k] bf16, swizzled
  __shared__ __align__(16) unsigned short ktvt[2][64][40];  // phase1: kt alias; phase4: vt dbuf
  __shared__ float redmax[4][16][2], redsum[4][16][2];

  unsigned short* kt_lds = &ktvt[0][0][0];   // [2][2][1024] u16 = 8192 u16, fits in 5120*... (see note)
  // NOTE: kt needs 4096 u16 * 2 buf = 8192 u16 = 16 KB? No: [2][2][1024] = 4096 u16 = 8 KB.
  // ktvt = 2*64*40 = 5120 u16 = 10 KB >= 8 KB. OK.

  const int tid = threadIdx.x, l = tid & 63, wid = tid >> 6;
  const int qg = wid >> 1, half = wid & 1;   // phase 4 reinterprets half as dh
  const int head = blockIdx.x >> 4, qb = blockIdx.x & 15;
  const int b = head >> 4, hh = head & 15;

  // ---- Phase 1: QK^T --------------------------------------------------------
  sx8 qf[2];
  {
    const int lqa = qb * 64 + qg * 16 + (l & 15);
    const size_t qoff = (size_t)(lqa * 8 + b) * 1024 + hh * 64 + (l >> 4) * 8;
    qf[0] = *(const sx8*)&q16[qoff];
    qf[1] = *(const sx8*)&q16[qoff + 32];
  }

  fx4 acc[32];
  #pragma unroll
  for (int s = 0; s < 32; ++s) acc[s] = fx4{0.f, 0.f, 0.f, 0.f};

  auto stage_k = [&](int buf, int s) {
    if (tid < 256) {
      const int half_s = tid >> 7, i = tid & 127;
      const int row = i >> 3, cphys = i & 7;
      const int clog = cphys ^ (row & 7);          // pre-swizzled source
      const int lk = half_s * 512 + s * 16 + row;
      gload_lds16(k16 + (size_t)(lk * 8 + b) * 1024 + hh * 64 + clog * 8,
                  &kt_lds[(buf * 2 + half_s) * 1024 + i * 8]);
    }
  };

  stage_k(0, 0);
  __syncthreads();
  #pragma unroll
  for (int s = 0; s < 32; ++s) {
    const int buf = s & 1;
    if (s + 1 < 32) stage_k(buf ^ 1, s + 1);
    sx8 bh0, bh1;
    {
      const int row = l & 15;
      const int c0 = (0 * 4 + (l >> 4)) ^ (row & 7);
      const int c1 = (1 * 4 + (l >> 4)) ^ (row & 7);
      bh0 = *(const sx8*)&kt_lds[(buf * 2 + half) * 1024 + row * 64 + c0 * 8];
      bh1 = *(const sx8*)&kt_lds[(buf * 2 + half) * 1024 + row * 64 + c1 * 8];
    }
    acc[s] = mfma_h(qf[0], bh0, acc[s]);
    acc[s] = mfma_h(qf[1], bh1, acc[s]);
    __syncthreads();
  }

  // ---- Phase 2: softmax -----------------------------------------------------
  const int rg = l >> 4;
  float mloc[4] = {-3e38f, -3e38f, -3e38f, -3e38f};
  #pragma unroll
  for (int s = 0; s < 32; ++s)
    #pragma unroll
    for (int i = 0; i < 4; ++i) mloc[i] = fmaxf(mloc[i], acc[s][i]);
  #pragma unroll
  for (int msk = 1; msk <= 8; msk <<= 1)
    #pragma unroll
    for (int i = 0; i < 4; ++i) mloc[i] = fmaxf(mloc[i], __shfl_xor(mloc[i], msk));
  if ((l & 15) == 0) {
    #pragma unroll
    for (int i = 0; i < 4; ++i) redmax[qg][rg * 4 + i][half] = mloc[i];
  }
  __syncthreads();
  float mfull[4], sloc[4] = {0.f, 0.f, 0.f, 0.f};
  #pragma unroll
  for (int i = 0; i < 4; ++i)
    mfull[i] = fmaxf(redmax[qg][rg * 4 + i][0], redmax[qg][rg * 4 + i][1]);
  #pragma unroll
  for (int s = 0; s < 32; ++s)
    #pragma unroll
    for (int i = 0; i < 4; ++i) {
      const float e = __expf(acc[s][i] - mfull[i]);
      acc[s][i] = e;
      sloc[i] += e;
    }
  #pragma unroll
  for (int msk = 1; msk <= 8; msk <<= 1)
    #pragma unroll
    for (int i = 0; i < 4; ++i) sloc[i] += __shfl_xor(sloc[i], msk);
  if ((l & 15) == 0) {
    #pragma unroll
    for (int i = 0; i < 4; ++i) redsum[qg][rg * 4 + i][half] = sloc[i];
  }
  __syncthreads();
  float inv[4];
  #pragma unroll
  for (int i = 0; i < 4; ++i)
    inv[i] = 1.0f / (redsum[qg][rg * 4 + i][0] + redsum[qg][rg * 4 + i][1]);

  // ---- Phase 3: probs -> global (f32) + P -> LDS (bf16, swizzled) ----------
  const size_t pbase = (size_t)head * 1048576;
  const int rloc = qg * 16 + rg * 4;            // local q row base (0..63)
  const int lqs = qb * 64 + rloc;               // global q row base
  #pragma unroll
  for (int s = 0; s < 32; ++s)
    #pragma unroll
    for (int i = 0; i < 4; ++i) {
      const float p = acc[s][i] * inv[i];
      const int c = half * 512 + s * 16 + (l & 15);
      probsF[pbase + (size_t)(lqs + i) * 1024 + c] = p;
      const int row = rloc + i;
      Pl[row * 1024 + (c ^ ((row & 7) << 3))] = f2bf_rne(p);
    }

  // ---- Phase 4: ctx = P @ V -------------------------------------------------
  auto stage_v = [&](int buf, int kc) {
    if (tid < 256) {
      const int kl = tid >> 3, d0 = (tid & 7) * 8;
      sx8 vv = *(const sx8*)&v_[(size_t)((kc * 32 + kl) * 8 + b) * 1024 + hh * 64 + d0];
      #pragma unroll
      for (int j = 0; j < 8; ++j) ktvt[buf][d0 + j][kl] = (unsigned short)vv[j];
    }
  };

  stage_v(0, 0);
  __syncthreads();

  const int dh = half;
  fx4 cacc[2] = {};
  for (int kc = 0; kc < 32; ++kc) {
    const int buf = kc & 1;
    if (kc + 1 < 32) stage_v(buf ^ 1, kc + 1);
    const int prow = qg * 16 + (l & 15);
    const int cb = kc * 32 + (l >> 4) * 8;
    sx8 pa = *(const sx8*)&Pl[prow * 1024 + (cb ^ ((prow & 7) << 3))];
    sx8 b0 = *(const sx8*)&ktvt[buf][dh * 32 + (l & 15)][(l >> 4) * 8];
    sx8 b1 = *(const sx8*)&ktvt[buf][dh * 32 + 16 + (l & 15)][(l >> 4) * 8];
    cacc[0] = mfma_b(pa, b0, cacc[0]);
    cacc[1] = mfma_b(pa, b1, cacc[1]);
    __syncthreads();
  }

  #pragma unroll
  for (int ni = 0; ni < 2; ++ni)
    #pragma unroll
    for (int i = 0; i < 4; ++i) {
      const int q = qb * 64 + qg * 16 + (l >> 4) * 4 + i;
      const int d = dh * 32 + ni * 16 + (l & 15);
      ctx[(size_t)(q * 8 + b) * 1024 + hh * 64 + d] = f2bf_rne(cacc[ni][i]);
    }
}

// ---------------------------------------------------------------------------
extern "C" void kernel_launch(void* const* d_in, const int* in_sizes, int n_in,
                              void* d_out, int out_size, void* d_ws, size_t ws_size,
                              hipStream_t stream)
{
  const float* query = (const float*)d_in[0];
  const float* key   = (const float*)d_in[1];
  const float* wq    = (const float*)d_in[2];
  const float* wkv   = (const float*)d_in[3];
  const float* wo    = (const float*)d_in[4];
  const float* r_q   = (const float*)d_in[5];
  const float* s_q   = (const float*)d_in[6];
  const float* r_kv  = (const float*)d_in[7];
  const float* s_kv  = (const float*)d_in[8];
  const float* r_o   = (const float*)d_in[9];
  const float* s_o   = (const float*)d_in[10];
  const float* rm_q  = (const float*)d_in[11];
  const float* sm_q  = (const float*)d_in[12];
  const float* rm_kv = (const float*)d_in[13];
  const float* sm_kv = (const float*)d_in[14];
  const float* rm_o  = (const float*)d_in[15];
  const float* sm_o  = (const float*)d_in[16];
  const int* src_i   = (const int*)d_in[17];
  const int* tgt_i   = (const int*)d_in[18];

  unsigned short* ws16 = (unsigned short*)d_ws;
  const size_t M1 = 1048576, M8 = 8388608;
  unsigned short* Wq16 = ws16;
  unsigned short* Wk16 = ws16 + M1;
  unsigned short* Wv   = ws16 + 2 * M1;
  unsigned short* Wo   = ws16 + 3 * M1;
  unsigned short* q16  = ws16 + 4 * M1;
  unsigned short* k16  = ws16 + 4 * M1 + M8;
  unsigned short* v_   = ws16 + 4 * M1 + 2 * M8;
  unsigned short* ctx  = ws16 + 4 * M1 + 3 * M8;   // total ~72 MB

  float* outF   = (float*)d_out;            // out: 8388608 f32
  float* probsF = outF + M8;                // probs: 134217728 f32

  k_build_w<<<dim3(16384), dim3(256), 0, stream>>>(
      wq, wkv, wo, r_q, s_q, r_kv, s_kv, r_o, s_o,
      rm_q, sm_q, rm_kv, sm_kv, rm_o, sm_o, src_i, tgt_i,
      Wq16, Wk16, Wv, Wo);

  k_gemm<0><<<dim3(8, 64), dim3(256), 0, stream>>>(query, nullptr, Wq16, q16, nullptr);
  k_gemm<0><<<dim3(8, 64), dim3(256), 0, stream>>>(key,   nullptr, Wk16, k16, nullptr);
  k_gemm<1><<<dim3(8, 64), dim3(256), 0, stream>>>(key,   nullptr, Wv,   v_,  nullptr);

  k_attn<<<dim3(2048), dim3(512), 0, stream>>>(q16, k16, v_, probsF, ctx);

  k_gemm<2><<<dim3(8, 64), dim3(256), 0, stream>>>(nullptr, ctx, Wo, nullptr, outF);
}

// Round 4
// 438.676 us; speedup vs baseline: 1.4312x; 1.4022x over previous
//
#include <hip/hip_runtime.h>
#include <hip/hip_bf16.h>

// MFW encdec multihead attention, MI355X.
// Pipeline: build W (lowrank-adapted) -> fp16 GEMM q,k -> bf16 GEMM v ->
// FUSED attn: K preloaded to LDS (no-barrier QK^T) -> softmax -> P->LDS bf16
// -> coalesced probs f32 write -> PV with register-prefetched V.
// d_out is FLOAT32: [out 8.4M | probs 134.2M].

typedef float  fx4 __attribute__((ext_vector_type(4)));
typedef short  sx8 __attribute__((ext_vector_type(8)));
typedef _Float16 hx8 __attribute__((ext_vector_type(8)));

__device__ __forceinline__ unsigned short f2bf_rne(float f) {
  unsigned u = __builtin_bit_cast(unsigned, f);
  u += 0x7FFFu + ((u >> 16) & 1u);
  return (unsigned short)(u >> 16);
}
__device__ __forceinline__ unsigned short f2h(float f) {
  return __builtin_bit_cast(unsigned short, (_Float16)f);
}
__device__ __forceinline__ float bf2f(unsigned v) {
  return __builtin_bit_cast(float, v << 16);
}

__device__ __forceinline__ void gload_lds16(const void* g, void* l) {
  __builtin_amdgcn_global_load_lds((const __attribute__((address_space(1))) void*)g,
                                   (__attribute__((address_space(3))) void*)l, 16, 0, 0);
}

__device__ __forceinline__ fx4 mfma_h(sx8 a, sx8 b, fx4 c) {
  return __builtin_amdgcn_mfma_f32_16x16x32_f16(__builtin_bit_cast(hx8, a),
                                                __builtin_bit_cast(hx8, b), c, 0, 0, 0);
}
__device__ __forceinline__ fx4 mfma_b(sx8 a, sx8 b, fx4 c) {
  return __builtin_amdgcn_mfma_f32_16x16x32_bf16(a, b, c, 0, 0, 0);
}

// ---------------------------------------------------------------------------
// Kernel 1: build adapted weights.
// mat 0: Wq (fp16, scaled by 0.125)  1: Wk (fp16)  2: Wv (bf16)  3: Wo (bf16)
// ---------------------------------------------------------------------------
__global__ void k_build_w(
    const float* wq, const float* wkv, const float* wo,
    const float* r_q, const float* s_q, const float* r_kv, const float* s_kv,
    const float* r_o, const float* s_o,
    const float* rm_q, const float* sm_q, const float* rm_kv, const float* sm_kv,
    const float* rm_o, const float* sm_o,
    const int* src_i, const int* tgt_i,
    unsigned short* Wq16, unsigned short* Wk16, unsigned short* Wv, unsigned short* Wo)
{
  const int it = tgt_i[0], is = src_i[0];
  const int gid = blockIdx.x * 256 + threadIdx.x;   // 0 .. 4*1024*1024-1
  const int mat = gid >> 20;
  const int idx = gid & 1048575;
  const int o = idx >> 10, i = idx & 1023;
  float lrm = 0.f, lr = 0.f, w;
  if (mat == 0) {
    #pragma unroll
    for (int r = 0; r < 4; ++r) {
      lrm += rm_q[(it * 4 + r) * 1024 + o] * sm_q[(is * 4 + r) * 1024 + i];
      lr  += r_q [(it * 4 + r) * 1024 + o] * s_q [(is * 4 + r) * 1024 + i];
    }
    w = (wq[idx] * lrm + lr) * 0.125f;   // fold q scaling into Wq
    Wq16[idx] = f2h(w);
  } else if (mat == 1) {
    #pragma unroll
    for (int r = 0; r < 4; ++r) {
      lrm += rm_kv[(it * 4 + r) * 2048 + o] * sm_kv[(is * 4 + r) * 1024 + i];
      lr  += r_kv [(it * 4 + r) * 2048 + o] * s_kv [(is * 4 + r) * 1024 + i];
    }
    w = wkv[idx] * lrm + lr;
    Wk16[idx] = f2h(w);
  } else if (mat == 2) {
    #pragma unroll
    for (int r = 0; r < 4; ++r) {
      lrm += rm_kv[(it * 4 + r) * 2048 + 1024 + o] * sm_kv[(is * 4 + r) * 1024 + i];
      lr  += r_kv [(it * 4 + r) * 2048 + 1024 + o] * s_kv [(is * 4 + r) * 1024 + i];
    }
    w = wkv[1048576 + idx] * lrm + lr;
    Wv[idx] = f2bf_rne(w);
  } else {
    #pragma unroll
    for (int r = 0; r < 4; ++r) {
      lrm += rm_o[(it * 4 + r) * 1024 + o] * sm_o[(is * 4 + r) * 1024 + i];
      lr  += r_o [(it * 4 + r) * 1024 + o] * s_o [(is * 4 + r) * 1024 + i];
    }
    w = wo[idx] * lrm + lr;
    Wo[idx] = f2bf_rne(w);
  }
}

// ---------------------------------------------------------------------------
// Kernel 2: C = A * B^T, M=8192, N=1024, K=1024.  128x128 tile, BK=32, 4 waves.
// MODE 0: A f32 -> fp16 staged, B fp16, C fp16       (q / k projections)
// MODE 1: A f32 -> bf16 staged, B bf16, C bf16       (v projection)
// MODE 2: A bf16 (global_load_lds), B bf16, C f32    (out projection -> d_out)
// ---------------------------------------------------------------------------
template<int MODE>
__global__ __launch_bounds__(256, 2) void k_gemm(
    const float* Af, const unsigned short* Ab,
    const unsigned short* Bmat, unsigned short* Ch, float* Cf)
{
  __shared__ unsigned short lds[2][2][4096];   // [buf][A=0/B=1][128*32]
  const int tid = threadIdx.x;
  const int l = tid & 63, wid = tid >> 6;
  const int wr = wid >> 1, wc = wid & 1;
  const int mBase = blockIdx.y * 128, nBase = blockIdx.x * 128;

  const int arow = tid >> 1, ac16 = (tid & 1) * 16;
  const int brow = tid >> 2, bc8 = (tid & 3) * 8;

  fx4 acc[4][4] = {};

  auto stage = [&](int buf, int kt) {
    const int kB = kt * 32;
    gload_lds16(Bmat + (size_t)(nBase + brow) * 1024 + kB + bc8,      &lds[buf][1][tid * 8]);
    gload_lds16(Bmat + (size_t)(nBase + 64 + brow) * 1024 + kB + bc8, &lds[buf][1][2048 + tid * 8]);
    if constexpr (MODE == 2) {
      gload_lds16(Ab + (size_t)(mBase + brow) * 1024 + kB + bc8,      &lds[buf][0][tid * 8]);
      gload_lds16(Ab + (size_t)(mBase + 64 + brow) * 1024 + kB + bc8, &lds[buf][0][2048 + tid * 8]);
    } else {
      const float* asrc = Af + (size_t)(mBase + arow) * 1024 + kB + ac16;
      sx8 h0, h1;
      #pragma unroll
      for (int p = 0; p < 4; ++p) {
        fx4 vv = *(const fx4*)(asrc + p * 4);
        #pragma unroll
        for (int j = 0; j < 4; ++j) {
          unsigned short hv;
          if constexpr (MODE == 0) hv = f2h(vv[j]); else hv = f2bf_rne(vv[j]);
          const int pos = p * 4 + j;
          if (pos < 8) h0[pos] = (short)hv; else h1[pos - 8] = (short)hv;
        }
      }
      *(sx8*)&lds[buf][0][arow * 32 + ac16]     = h0;
      *(sx8*)&lds[buf][0][arow * 32 + ac16 + 8] = h1;
    }
  };

  auto compute = [&](int buf) {
    sx8 af[4], bfv[4];
    #pragma unroll
    for (int x = 0; x < 4; ++x) {
      af[x]  = *(const sx8*)&lds[buf][0][(wr * 64 + x * 16 + (l & 15)) * 32 + (l >> 4) * 8];
      bfv[x] = *(const sx8*)&lds[buf][1][(wc * 64 + x * 16 + (l & 15)) * 32 + (l >> 4) * 8];
    }
    #pragma unroll
    for (int mi = 0; mi < 4; ++mi)
      #pragma unroll
      for (int ni = 0; ni < 4; ++ni) {
        if constexpr (MODE == 0) acc[mi][ni] = mfma_h(af[mi], bfv[ni], acc[mi][ni]);
        else                     acc[mi][ni] = mfma_b(af[mi], bfv[ni], acc[mi][ni]);
      }
  };

  stage(0, 0);
  __syncthreads();
  for (int kt = 0; kt < 32; ++kt) {
    const int buf = kt & 1;
    if (kt + 1 < 32) stage(buf ^ 1, kt + 1);
    compute(buf);
    __syncthreads();
  }

  #pragma unroll
  for (int mi = 0; mi < 4; ++mi)
    #pragma unroll
    for (int ni = 0; ni < 4; ++ni)
      #pragma unroll
      for (int i = 0; i < 4; ++i) {
        const size_t row = (size_t)(mBase + wr * 64 + mi * 16 + (l >> 4) * 4 + i);
        const size_t col = (size_t)(nBase + wc * 64 + ni * 16 + (l & 15));
        const float x = acc[mi][ni][i];
        if constexpr (MODE == 0)      Ch[row * 1024 + col] = f2h(x);
        else if constexpr (MODE == 1) Ch[row * 1024 + col] = f2bf_rne(x);
        else                          Cf[row * 1024 + col] = x;
      }
}

// ---------------------------------------------------------------------------
// Kernel 3 (FUSED attn v2). Block = (head, 64 q), 512 threads, 8 waves.
// Phase 0: preload entire K-slice (1024x64, 128 KB) into Pl, chunk-swizzled.
// Phase 1: QK^T with ZERO barriers (wave (qg,half): 16 q x 512 k, 64 MFMA).
// Phase 2: exact softmax (shfl 16-groups + cross-half LDS).
// Phase 3a: P bf16 -> Pl (overwrites K) [64 q][1024 k], chunk-XOR swizzle.
// Phase 3b: coalesced probs f32 write (read Pl rows, dwordx4 stores);
//           all 16 V-chunks issued to registers before 3b (latency hidden).
// Phase 4: PV, 16 iters: vt write from regs -> bar -> 4 MFMA/wave -> bar.
// LDS ~141 KB -> 1 block/CU.
// ---------------------------------------------------------------------------
__global__ __launch_bounds__(512, 2) void k_attn(
    const unsigned short* q16, const unsigned short* k16,
    const unsigned short* v_, float* probsF, unsigned short* ctx)
{
  __shared__ __align__(16) unsigned short Pl[65536];    // K-cache, then P
  __shared__ __align__(16) unsigned short vt[64 * 72];  // V^T chunk [64 d][64 k + 8 pad]
  __shared__ float redmax[4][16][2], redsum[4][16][2];

  const int tid = threadIdx.x, l = tid & 63, wid = tid >> 6;
  const int qg = wid >> 1, half = wid & 1;   // phase 4 reuses half as dh
  const int head = blockIdx.x >> 4, qb = blockIdx.x & 15;
  const int b = head >> 4, hh = head & 15;

  // ---- Phase 0: K preload (pre-swizzled source, linear LDS dest) ----------
  #pragma unroll
  for (int r = 0; r < 16; ++r) {
    const int e = r * 512 + tid;
    const int lk = e >> 3, ch = e & 7;
    gload_lds16(k16 + (size_t)(lk * 8 + b) * 1024 + hh * 64 + ((ch ^ (lk & 7)) * 8),
                &Pl[e * 8]);
  }

  sx8 qf[2];
  {
    const int lqa = qb * 64 + qg * 16 + (l & 15);
    const size_t qoff = (size_t)(lqa * 8 + b) * 1024 + hh * 64 + (l >> 4) * 8;
    qf[0] = *(const sx8*)&q16[qoff];
    qf[1] = *(const sx8*)&q16[qoff + 32];
  }
  __syncthreads();

  // ---- Phase 1: QK^T, no barriers -----------------------------------------
  fx4 acc[32];
  #pragma unroll
  for (int s = 0; s < 32; ++s) acc[s] = fx4{0.f, 0.f, 0.f, 0.f};

  #pragma unroll
  for (int s = 0; s < 32; ++s) {
    const int lk = half * 512 + s * 16 + (l & 15);
    const int c0 = ((l >> 4)) ^ (lk & 7);
    const int c1 = (4 + (l >> 4)) ^ (lk & 7);
    sx8 bh0 = *(const sx8*)&Pl[lk * 64 + c0 * 8];
    sx8 bh1 = *(const sx8*)&Pl[lk * 64 + c1 * 8];
    acc[s] = mfma_h(qf[0], bh0, acc[s]);
    acc[s] = mfma_h(qf[1], bh1, acc[s]);
  }

  // ---- Phase 2: softmax ---------------------------------------------------
  const int rg = l >> 4;
  float mloc[4] = {-3e38f, -3e38f, -3e38f, -3e38f};
  #pragma unroll
  for (int s = 0; s < 32; ++s)
    #pragma unroll
    for (int i = 0; i < 4; ++i) mloc[i] = fmaxf(mloc[i], acc[s][i]);
  #pragma unroll
  for (int msk = 1; msk <= 8; msk <<= 1)
    #pragma unroll
    for (int i = 0; i < 4; ++i) mloc[i] = fmaxf(mloc[i], __shfl_xor(mloc[i], msk));
  if ((l & 15) == 0) {
    #pragma unroll
    for (int i = 0; i < 4; ++i) redmax[qg][rg * 4 + i][half] = mloc[i];
  }
  __syncthreads();                                   // (A) also: all K reads done
  float mfull[4], sloc[4] = {0.f, 0.f, 0.f, 0.f};
  #pragma unroll
  for (int i = 0; i < 4; ++i)
    mfull[i] = fmaxf(redmax[qg][rg * 4 + i][0], redmax[qg][rg * 4 + i][1]);
  #pragma unroll
  for (int s = 0; s < 32; ++s)
    #pragma unroll
    for (int i = 0; i < 4; ++i) {
      const float e = __expf(acc[s][i] - mfull[i]);
      acc[s][i] = e;
      sloc[i] += e;
    }
  #pragma unroll
  for (int msk = 1; msk <= 8; msk <<= 1)
    #pragma unroll
    for (int i = 0; i < 4; ++i) sloc[i] += __shfl_xor(sloc[i], msk);
  if ((l & 15) == 0) {
    #pragma unroll
    for (int i = 0; i < 4; ++i) redsum[qg][rg * 4 + i][half] = sloc[i];
  }
  __syncthreads();                                   // (B)
  float inv[4];
  #pragma unroll
  for (int i = 0; i < 4; ++i)
    inv[i] = 1.0f / (redsum[qg][rg * 4 + i][0] + redsum[qg][rg * 4 + i][1]);

  // ---- Phase 3a: P (bf16, swizzled) -> Pl (K no longer needed) ------------
  const int rloc = qg * 16 + rg * 4;
  #pragma unroll
  for (int s = 0; s < 32; ++s)
    #pragma unroll
    for (int i = 0; i < 4; ++i) {
      const int c = half * 512 + s * 16 + (l & 15);
      const int row = rloc + i;
      Pl[row * 1024 + (c ^ ((row & 7) << 3))] = f2bf_rne(acc[s][i] * inv[i]);
    }
  __syncthreads();                                   // (C) P complete

  // ---- issue all V-chunk loads to registers (hidden under 3b) -------------
  sx8 vreg[16];
  {
    const int kl = tid >> 3, d0 = (tid & 7) * 8;
    #pragma unroll
    for (int kc = 0; kc < 16; ++kc)
      vreg[kc] = *(const sx8*)&v_[(size_t)((kc * 64 + kl) * 8 + b) * 1024 + hh * 64 + d0];
  }

  // ---- Phase 3b: coalesced probs f32 write from Pl ------------------------
  {
    const size_t pbase = (size_t)head * 1048576;
    #pragma unroll
    for (int r8 = 0; r8 < 8; ++r8) {
      const int r = wid * 8 + r8;
      float* grow = probsF + pbase + (size_t)(qb * 64 + r) * 1024;
      #pragma unroll
      for (int st = 0; st < 4; ++st) {
        const int c = st * 256 + l * 4;
        const unsigned* raw = (const unsigned*)&Pl[r * 1024 + (c ^ ((r & 7) << 3))];
        const unsigned r0 = raw[0], r1 = raw[1];
        fx4 o;
        o[0] = bf2f(r0 & 0xffffu); o[1] = bf2f(r0 >> 16);
        o[2] = bf2f(r1 & 0xffffu); o[3] = bf2f(r1 >> 16);
        *(fx4*)&grow[c] = o;
      }
    }
  }

  // ---- Phase 4: ctx = P @ V ----------------------------------------------
  const int dh = half;
  fx4 cacc[2] = {};
  {
    const int kl = tid >> 3, d0 = (tid & 7) * 8;
    #pragma unroll
    for (int kc = 0; kc < 16; ++kc) {
      #pragma unroll
      for (int j = 0; j < 8; ++j)
        vt[(d0 + j) * 72 + kl] = (unsigned short)vreg[kc][j];
      __syncthreads();
      #pragma unroll
      for (int kk = 0; kk < 2; ++kk) {
        const int prow = qg * 16 + (l & 15);
        const int pcol = kc * 64 + kk * 32 + (l >> 4) * 8;
        sx8 pa = *(const sx8*)&Pl[prow * 1024 + (pcol ^ ((prow & 7) << 3))];
        #pragma unroll
        for (int ni = 0; ni < 2; ++ni) {
          sx8 vb = *(const sx8*)&vt[(dh * 32 + ni * 16 + (l & 15)) * 72 + kk * 32 + (l >> 4) * 8];
          cacc[ni] = mfma_b(pa, vb, cacc[ni]);
        }
      }
      __syncthreads();
    }
  }

  #pragma unroll
  for (int ni = 0; ni < 2; ++ni)
    #pragma unroll
    for (int i = 0; i < 4; ++i) {
      const int q = qb * 64 + qg * 16 + (l >> 4) * 4 + i;
      const int d = dh * 32 + ni * 16 + (l & 15);
      ctx[(size_t)(q * 8 + b) * 1024 + hh * 64 + d] = f2bf_rne(cacc[ni][i]);
    }
}

// ---------------------------------------------------------------------------
extern "C" void kernel_launch(void* const* d_in, const int* in_sizes, int n_in,
                              void* d_out, int out_size, void* d_ws, size_t ws_size,
                              hipStream_t stream)
{
  const float* query = (const float*)d_in[0];
  const float* key   = (const float*)d_in[1];
  const float* wq    = (const float*)d_in[2];
  const float* wkv   = (const float*)d_in[3];
  const float* wo    = (const float*)d_in[4];
  const float* r_q   = (const float*)d_in[5];
  const float* s_q   = (const float*)d_in[6];
  const float* r_kv  = (const float*)d_in[7];
  const float* s_kv  = (const float*)d_in[8];
  const float* r_o   = (const float*)d_in[9];
  const float* s_o   = (const float*)d_in[10];
  const float* rm_q  = (const float*)d_in[11];
  const float* sm_q  = (const float*)d_in[12];
  const float* rm_kv = (const float*)d_in[13];
  const float* sm_kv = (const float*)d_in[14];
  const float* rm_o  = (const float*)d_in[15];
  const float* sm_o  = (const float*)d_in[16];
  const int* src_i   = (const int*)d_in[17];
  const int* tgt_i   = (const int*)d_in[18];

  unsigned short* ws16 = (unsigned short*)d_ws;
  const size_t M1 = 1048576, M8 = 8388608;
  unsigned short* Wq16 = ws16;
  unsigned short* Wk16 = ws16 + M1;
  unsigned short* Wv   = ws16 + 2 * M1;
  unsigned short* Wo   = ws16 + 3 * M1;
  unsigned short* q16  = ws16 + 4 * M1;
  unsigned short* k16  = ws16 + 4 * M1 + M8;
  unsigned short* v_   = ws16 + 4 * M1 + 2 * M8;
  unsigned short* ctx  = ws16 + 4 * M1 + 3 * M8;   // total ~72 MB

  float* outF   = (float*)d_out;            // out: 8388608 f32
  float* probsF = outF + M8;                // probs: 134217728 f32

  k_build_w<<<dim3(16384), dim3(256), 0, stream>>>(
      wq, wkv, wo, r_q, s_q, r_kv, s_kv, r_o, s_o,
      rm_q, sm_q, rm_kv, sm_kv, rm_o, sm_o, src_i, tgt_i,
      Wq16, Wk16, Wv, Wo);

  k_gemm<0><<<dim3(8, 64), dim3(256), 0, stream>>>(query, nullptr, Wq16, q16, nullptr);
  k_gemm<0><<<dim3(8, 64), dim3(256), 0, stream>>>(key,   nullptr, Wk16, k16, nullptr);
  k_gemm<1><<<dim3(8, 64), dim3(256), 0, stream>>>(key,   nullptr, Wv,   v_,  nullptr);

  k_attn<<<dim3(2048), dim3(512), 0, stream>>>(q16, k16, v_, probsF, ctx);

  k_gemm<2><<<dim3(8, 64), dim3(256), 0, stream>>>(nullptr, ctx, Wo, nullptr, outF);
}

// Round 5
// 394.330 us; speedup vs baseline: 1.5921x; 1.1125x over previous
//
#include <hip/hip_runtime.h>
#include <hip/hip_bf16.h>

// MFW encdec multihead attention, MI355X — all-fp16 pipeline.
// build W (fp16) -> cvt q/k f32->fp16 -> fused KV GEMM (N=2048) -> Q GEMM ->
// fused attn (K-preload LDS, no-barrier QK^T, softmax, probs f32 out,
// PV with lgkm-only barriers so probs stores drain under PV) -> out GEMM.
// d_out is FLOAT32: [out 8.4M | probs 134.2M].

typedef float  fx4 __attribute__((ext_vector_type(4)));
typedef short  sx8 __attribute__((ext_vector_type(8)));
typedef _Float16 hx8 __attribute__((ext_vector_type(8)));

__device__ __forceinline__ unsigned short f2h(float f) {
  return __builtin_bit_cast(unsigned short, (_Float16)f);
}
__device__ __forceinline__ float h2f(unsigned short h) {
  return (float)__builtin_bit_cast(_Float16, h);
}

__device__ __forceinline__ void gload_lds16(const void* g, void* l) {
  __builtin_amdgcn_global_load_lds((const __attribute__((address_space(1))) void*)g,
                                   (__attribute__((address_space(3))) void*)l, 16, 0, 0);
}

__device__ __forceinline__ fx4 mfma_h(sx8 a, sx8 b, fx4 c) {
  return __builtin_amdgcn_mfma_f32_16x16x32_f16(__builtin_bit_cast(hx8, a),
                                                __builtin_bit_cast(hx8, b), c, 0, 0, 0);
}

// barrier that does NOT drain vmcnt (lets global stores stay in flight)
__device__ __forceinline__ void bar_lgkm() {
  __builtin_amdgcn_sched_barrier(0);
  asm volatile("s_waitcnt lgkmcnt(0)" ::: "memory");
  __builtin_amdgcn_s_barrier();
  __builtin_amdgcn_sched_barrier(0);
}

// ---------------------------------------------------------------------------
// Kernel 1: build adapted weights (all fp16).
// mat 0: Wq (x0.125) -> Wq16   1: Wk -> Wkv16 rows 0..1023
// mat 2: Wv -> Wkv16 rows 1024..2047   3: Wo -> Wo16
// ---------------------------------------------------------------------------
__global__ void k_build_w(
    const float* wq, const float* wkv, const float* wo,
    const float* r_q, const float* s_q, const float* r_kv, const float* s_kv,
    const float* r_o, const float* s_o,
    const float* rm_q, const float* sm_q, const float* rm_kv, const float* sm_kv,
    const float* rm_o, const float* sm_o,
    const int* src_i, const int* tgt_i,
    unsigned short* Wq16, unsigned short* Wkv16, unsigned short* Wo16)
{
  const int it = tgt_i[0], is = src_i[0];
  const int gid = blockIdx.x * 256 + threadIdx.x;   // 0 .. 4M-1
  const int mat = gid >> 20;
  const int idx = gid & 1048575;
  const int o = idx >> 10, i = idx & 1023;
  float lrm = 0.f, lr = 0.f;
  if (mat == 0) {
    #pragma unroll
    for (int r = 0; r < 4; ++r) {
      lrm += rm_q[(it * 4 + r) * 1024 + o] * sm_q[(is * 4 + r) * 1024 + i];
      lr  += r_q [(it * 4 + r) * 1024 + o] * s_q [(is * 4 + r) * 1024 + i];
    }
    Wq16[idx] = f2h((wq[idx] * lrm + lr) * 0.125f);
  } else if (mat == 1) {
    #pragma unroll
    for (int r = 0; r < 4; ++r) {
      lrm += rm_kv[(it * 4 + r) * 2048 + o] * sm_kv[(is * 4 + r) * 1024 + i];
      lr  += r_kv [(it * 4 + r) * 2048 + o] * s_kv [(is * 4 + r) * 1024 + i];
    }
    Wkv16[idx] = f2h(wkv[idx] * lrm + lr);
  } else if (mat == 2) {
    #pragma unroll
    for (int r = 0; r < 4; ++r) {
      lrm += rm_kv[(it * 4 + r) * 2048 + 1024 + o] * sm_kv[(is * 4 + r) * 1024 + i];
      lr  += r_kv [(it * 4 + r) * 2048 + 1024 + o] * s_kv [(is * 4 + r) * 1024 + i];
    }
    Wkv16[1048576 + idx] = f2h(wkv[1048576 + idx] * lrm + lr);
  } else {
    #pragma unroll
    for (int r = 0; r < 4; ++r) {
      lrm += rm_o[(it * 4 + r) * 1024 + o] * sm_o[(is * 4 + r) * 1024 + i];
      lr  += r_o [(it * 4 + r) * 1024 + o] * s_o [(is * 4 + r) * 1024 + i];
    }
    Wo16[idx] = f2h(wo[idx] * lrm + lr);
  }
}

// ---------------------------------------------------------------------------
// Kernel 1b: convert query/key f32 -> fp16 (vectorized, 8 elems/thread).
// ---------------------------------------------------------------------------
__global__ void k_cvt(const float* q, const float* k,
                      unsigned short* qh, unsigned short* kh)
{
  const int gid = blockIdx.x * 256 + threadIdx.x;   // 0 .. 2M-1
  const bool isq = gid < 1048576;
  const size_t off = (size_t)(isq ? gid : gid - 1048576) * 8;
  const float* s = (isq ? q : k) + off;
  unsigned short* d = (isq ? qh : kh) + off;
  fx4 a = *(const fx4*)s, bv = *(const fx4*)(s + 4);
  sx8 h;
  #pragma unroll
  for (int j = 0; j < 4; ++j) { h[j] = (short)f2h(a[j]); h[4 + j] = (short)f2h(bv[j]); }
  *(sx8*)d = h;
}

// ---------------------------------------------------------------------------
// Kernel 2: C = A * B^T.  A fp16 [8192][1024], B fp16 [N][1024].
// 128x128 tile, BK=32, 4 waves, m97 structure (global_load_lds width 16).
// NS = C row stride; F32OUT: store f32 (else fp16).
// ---------------------------------------------------------------------------
template<int NS, bool F32OUT>
__global__ __launch_bounds__(256, 2) void k_gemm(
    const unsigned short* A, const unsigned short* B,
    unsigned short* Ch, float* Cf)
{
  __shared__ unsigned short lds[2][2][4096];   // [buf][A=0/B=1][128*32]
  const int tid = threadIdx.x;
  const int l = tid & 63, wid = tid >> 6;
  const int wr = wid >> 1, wc = wid & 1;
  const int mBase = blockIdx.y * 128, nBase = blockIdx.x * 128;
  const int brow = tid >> 2, bc8 = (tid & 3) * 8;

  fx4 acc[4][4] = {};

  auto stage = [&](int buf, int kt) {
    const int kB = kt * 32;
    gload_lds16(B + (size_t)(nBase + brow) * 1024 + kB + bc8,      &lds[buf][1][tid * 8]);
    gload_lds16(B + (size_t)(nBase + 64 + brow) * 1024 + kB + bc8, &lds[buf][1][2048 + tid * 8]);
    gload_lds16(A + (size_t)(mBase + brow) * 1024 + kB + bc8,      &lds[buf][0][tid * 8]);
    gload_lds16(A + (size_t)(mBase + 64 + brow) * 1024 + kB + bc8, &lds[buf][0][2048 + tid * 8]);
  };

  auto compute = [&](int buf) {
    sx8 af[4], bfv[4];
    #pragma unroll
    for (int x = 0; x < 4; ++x) {
      af[x]  = *(const sx8*)&lds[buf][0][(wr * 64 + x * 16 + (l & 15)) * 32 + (l >> 4) * 8];
      bfv[x] = *(const sx8*)&lds[buf][1][(wc * 64 + x * 16 + (l & 15)) * 32 + (l >> 4) * 8];
    }
    #pragma unroll
    for (int mi = 0; mi < 4; ++mi)
      #pragma unroll
      for (int ni = 0; ni < 4; ++ni)
        acc[mi][ni] = mfma_h(af[mi], bfv[ni], acc[mi][ni]);
  };

  stage(0, 0);
  __syncthreads();
  for (int kt = 0; kt < 32; ++kt) {
    const int buf = kt & 1;
    if (kt + 1 < 32) stage(buf ^ 1, kt + 1);
    compute(buf);
    __syncthreads();
  }

  #pragma unroll
  for (int mi = 0; mi < 4; ++mi)
    #pragma unroll
    for (int ni = 0; ni < 4; ++ni)
      #pragma unroll
      for (int i = 0; i < 4; ++i) {
        const size_t row = (size_t)(mBase + wr * 64 + mi * 16 + (l >> 4) * 4 + i);
        const size_t col = (size_t)(nBase + wc * 64 + ni * 16 + (l & 15));
        if constexpr (F32OUT) Cf[row * NS + col] = acc[mi][ni][i];
        else                  Ch[row * NS + col] = f2h(acc[mi][ni][i]);
      }
}

// ---------------------------------------------------------------------------
// Kernel 3 (FUSED attn, all fp16). Block = (head, 64 q), 512 threads, 8 waves.
// XCD swizzle: all 16 q-blocks of a head on one XCD (K/V re-reads -> L2 hits).
// Phase 0: preload K-slice (1024x64 fp16, 128 KB) into Pl, chunk-swizzled.
// Phase 1: QK^T, zero barriers (wave (qg,half): 16 q x 512 k).
// Phase 2: exact softmax.  Phase 3a: P fp16 -> Pl (overwrites K).
// Phase 3b: V-chunk loads to regs, then coalesced probs f32 stores.
// Phase 4: PV, vt double-buffer, ONE lgkm-only barrier/iter -> probs stores
//          drain in background.
// ---------------------------------------------------------------------------
__global__ __launch_bounds__(512, 2) void k_attn(
    const unsigned short* q16, const unsigned short* kv,
    float* probsF, unsigned short* ctx)
{
  __shared__ __align__(16) unsigned short Pl[65536];       // K-cache, then P
  __shared__ __align__(16) unsigned short vt[2][64 * 72];  // V^T chunk dbuf
  __shared__ float redmax[4][16][2], redsum[4][16][2];

  const int tid = threadIdx.x, l = tid & 63, wid = tid >> 6;
  const int qg = wid >> 1, half = wid & 1;   // phase 4 reuses half as dh
  const int bid = blockIdx.x;
  const int logical = (bid & 7) * 256 + (bid >> 3);   // XCD-grouped (bijective)
  const int head = logical >> 4, qb = logical & 15;
  const int b = head >> 4, hh = head & 15;

  // ---- Phase 0: K preload (pre-swizzled source, linear LDS dest) ----------
  #pragma unroll
  for (int r = 0; r < 16; ++r) {
    const int e = r * 512 + tid;
    const int lk = e >> 3, ch = e & 7;
    gload_lds16(kv + (size_t)(lk * 8 + b) * 2048 + hh * 64 + ((ch ^ (lk & 7)) * 8),
                &Pl[e * 8]);
  }

  sx8 qf[2];
  {
    const int lqa = qb * 64 + qg * 16 + (l & 15);
    const size_t qoff = (size_t)(lqa * 8 + b) * 1024 + hh * 64 + (l >> 4) * 8;
    qf[0] = *(const sx8*)&q16[qoff];
    qf[1] = *(const sx8*)&q16[qoff + 32];
  }
  __syncthreads();

  // ---- Phase 1: QK^T, no barriers -----------------------------------------
  fx4 acc[32];
  #pragma unroll
  for (int s = 0; s < 32; ++s) acc[s] = fx4{0.f, 0.f, 0.f, 0.f};

  #pragma unroll
  for (int s = 0; s < 32; ++s) {
    const int lk = half * 512 + s * 16 + (l & 15);
    const int c0 = ((l >> 4)) ^ (lk & 7);
    const int c1 = (4 + (l >> 4)) ^ (lk & 7);
    sx8 bh0 = *(const sx8*)&Pl[lk * 64 + c0 * 8];
    sx8 bh1 = *(const sx8*)&Pl[lk * 64 + c1 * 8];
    acc[s] = mfma_h(qf[0], bh0, acc[s]);
    acc[s] = mfma_h(qf[1], bh1, acc[s]);
  }

  // ---- Phase 2: softmax ---------------------------------------------------
  const int rg = l >> 4;
  float mloc[4] = {-3e38f, -3e38f, -3e38f, -3e38f};
  #pragma unroll
  for (int s = 0; s < 32; ++s)
    #pragma unroll
    for (int i = 0; i < 4; ++i) mloc[i] = fmaxf(mloc[i], acc[s][i]);
  #pragma unroll
  for (int msk = 1; msk <= 8; msk <<= 1)
    #pragma unroll
    for (int i = 0; i < 4; ++i) mloc[i] = fmaxf(mloc[i], __shfl_xor(mloc[i], msk));
  if ((l & 15) == 0) {
    #pragma unroll
    for (int i = 0; i < 4; ++i) redmax[qg][rg * 4 + i][half] = mloc[i];
  }
  __syncthreads();                                   // (A) + all K reads done
  float mfull[4], sloc[4] = {0.f, 0.f, 0.f, 0.f};
  #pragma unroll
  for (int i = 0; i < 4; ++i)
    mfull[i] = fmaxf(redmax[qg][rg * 4 + i][0], redmax[qg][rg * 4 + i][1]);
  #pragma unroll
  for (int s = 0; s < 32; ++s)
    #pragma unroll
    for (int i = 0; i < 4; ++i) {
      const float e = __expf(acc[s][i] - mfull[i]);
      acc[s][i] = e;
      sloc[i] += e;
    }
  #pragma unroll
  for (int msk = 1; msk <= 8; msk <<= 1)
    #pragma unroll
    for (int i = 0; i < 4; ++i) sloc[i] += __shfl_xor(sloc[i], msk);
  if ((l & 15) == 0) {
    #pragma unroll
    for (int i = 0; i < 4; ++i) redsum[qg][rg * 4 + i][half] = sloc[i];
  }
  __syncthreads();                                   // (B)
  float inv[4];
  #pragma unroll
  for (int i = 0; i < 4; ++i)
    inv[i] = 1.0f / (redsum[qg][rg * 4 + i][0] + redsum[qg][rg * 4 + i][1]);

  // ---- Phase 3a: P (fp16, swizzled) -> Pl ----------------------------------
  const int rloc = qg * 16 + rg * 4;
  #pragma unroll
  for (int s = 0; s < 32; ++s)
    #pragma unroll
    for (int i = 0; i < 4; ++i) {
      const int c = half * 512 + s * 16 + (l & 15);
      const int row = rloc + i;
      Pl[row * 1024 + (c ^ ((row & 7) << 3))] = f2h(acc[s][i] * inv[i]);
    }
  __syncthreads();                                   // (C) P complete

  // ---- V-chunk loads to registers (issued BEFORE probs stores) ------------
  sx8 vreg[16];
  {
    const int kl = tid >> 3, d0 = (tid & 7) * 8;
    #pragma unroll
    for (int kc = 0; kc < 16; ++kc)
      vreg[kc] = *(const sx8*)&kv[(size_t)((kc * 64 + kl) * 8 + b) * 2048 + 1024 + hh * 64 + d0];
  }

  // ---- Phase 3b: coalesced probs f32 stores from Pl ------------------------
  {
    const size_t pbase = (size_t)head * 1048576;
    #pragma unroll
    for (int r8 = 0; r8 < 8; ++r8) {
      const int r = wid * 8 + r8;
      float* grow = probsF + pbase + (size_t)(qb * 64 + r) * 1024;
      #pragma unroll
      for (int st = 0; st < 4; ++st) {
        const int c = st * 256 + l * 4;
        const unsigned* raw = (const unsigned*)&Pl[r * 1024 + (c ^ ((r & 7) << 3))];
        const unsigned r0 = raw[0], r1 = raw[1];
        fx4 o;
        o[0] = h2f((unsigned short)(r0 & 0xffffu)); o[1] = h2f((unsigned short)(r0 >> 16));
        o[2] = h2f((unsigned short)(r1 & 0xffffu)); o[3] = h2f((unsigned short)(r1 >> 16));
        *(fx4*)&grow[c] = o;
      }
    }
  }

  // ---- Phase 4: ctx = P @ V  (lgkm-only barriers; stores drain underneath) --
  const int dh = half;
  const int kl = tid >> 3, d0 = (tid & 7) * 8;
  fx4 cacc[2] = {};

  auto stage_vt = [&](int buf, int kc) {
    #pragma unroll
    for (int j = 0; j < 8; ++j)
      vt[buf][(d0 + j) * 72 + kl] = (unsigned short)vreg[kc][j];
  };

  stage_vt(0, 0);
  bar_lgkm();
  #pragma unroll
  for (int kc = 0; kc < 16; ++kc) {
    const int buf = kc & 1;
    if (kc + 1 < 16) stage_vt(buf ^ 1, kc + 1);
    #pragma unroll
    for (int kk = 0; kk < 2; ++kk) {
      const int prow = qg * 16 + (l & 15);
      const int pcol = kc * 64 + kk * 32 + (l >> 4) * 8;
      sx8 pa = *(const sx8*)&Pl[prow * 1024 + (pcol ^ ((prow & 7) << 3))];
      #pragma unroll
      for (int ni = 0; ni < 2; ++ni) {
        sx8 vb = *(const sx8*)&vt[buf][(dh * 32 + ni * 16 + (l & 15)) * 72 + kk * 32 + (l >> 4) * 8];
        cacc[ni] = mfma_h(pa, vb, cacc[ni]);
      }
    }
    bar_lgkm();
  }

  #pragma unroll
  for (int ni = 0; ni < 2; ++ni)
    #pragma unroll
    for (int i = 0; i < 4; ++i) {
      const int q = qb * 64 + qg * 16 + (l >> 4) * 4 + i;
      const int d = dh * 32 + ni * 16 + (l & 15);
      ctx[(size_t)(q * 8 + b) * 1024 + hh * 64 + d] = f2h(cacc[ni][i]);
    }
}

// ---------------------------------------------------------------------------
extern "C" void kernel_launch(void* const* d_in, const int* in_sizes, int n_in,
                              void* d_out, int out_size, void* d_ws, size_t ws_size,
                              hipStream_t stream)
{
  const float* query = (const float*)d_in[0];
  const float* key   = (const float*)d_in[1];
  const float* wq    = (const float*)d_in[2];
  const float* wkv   = (const float*)d_in[3];
  const float* wo    = (const float*)d_in[4];
  const float* r_q   = (const float*)d_in[5];
  const float* s_q   = (const float*)d_in[6];
  const float* r_kv  = (const float*)d_in[7];
  const float* s_kv  = (const float*)d_in[8];
  const float* r_o   = (const float*)d_in[9];
  const float* s_o   = (const float*)d_in[10];
  const float* rm_q  = (const float*)d_in[11];
  const float* sm_q  = (const float*)d_in[12];
  const float* rm_kv = (const float*)d_in[13];
  const float* sm_kv = (const float*)d_in[14];
  const float* rm_o  = (const float*)d_in[15];
  const float* sm_o  = (const float*)d_in[16];
  const int* src_i   = (const int*)d_in[17];
  const int* tgt_i   = (const int*)d_in[18];

  unsigned short* ws16 = (unsigned short*)d_ws;
  const size_t M1 = 1048576, M8 = 8388608;
  unsigned short* Wq16  = ws16;               // 1M
  unsigned short* Wkv16 = ws16 + M1;          // 2M
  unsigned short* Wo16  = ws16 + 3 * M1;      // 1M
  unsigned short* qh    = ws16 + 4 * M1;      // 8M (later reused as ctx)
  unsigned short* kh    = ws16 + 12 * M1;     // 8M (later reused as q16)
  unsigned short* kv16  = ws16 + 20 * M1;     // 16M  -> total 36M u16 = 72 MB
  unsigned short* q16   = kh;                 // q-proj overwrites kh (after KV GEMM)
  unsigned short* ctx   = qh;                 // ctx overwrites qh (after Q GEMM)

  float* outF   = (float*)d_out;              // out: 8388608 f32
  float* probsF = outF + M8;                  // probs: 134217728 f32

  k_build_w<<<dim3(16384), dim3(256), 0, stream>>>(
      wq, wkv, wo, r_q, s_q, r_kv, s_kv, r_o, s_o,
      rm_q, sm_q, rm_kv, sm_kv, rm_o, sm_o, src_i, tgt_i,
      Wq16, Wkv16, Wo16);

  k_cvt<<<dim3(8192), dim3(256), 0, stream>>>(query, key, qh, kh);

  // kv = key @ Wkv^T (N=2048) -- must precede Q GEMM (q16 aliases kh)
  k_gemm<2048, false><<<dim3(16, 64), dim3(256), 0, stream>>>(kh, Wkv16, kv16, nullptr);
  // q = query @ Wq^T (scaling folded into Wq)
  k_gemm<1024, false><<<dim3(8, 64), dim3(256), 0, stream>>>(qh, Wq16, q16, nullptr);

  k_attn<<<dim3(2048), dim3(512), 0, stream>>>(q16, kv16, probsF, ctx);

  // out = ctx @ Wo^T -> f32 d_out
  k_gemm<1024, true><<<dim3(8, 64), dim3(256), 0, stream>>>(ctx, Wo16, nullptr, outF);
}